// Round 1
// baseline (3280.727 us; speedup 1.0000x reference)
//
#include <hip/hip_runtime.h>
#include <hip/hip_bf16.h>

// Problem: B=2, T=2048, C=1024, H=16, HD=64, ALPHA=32
// Math note: softmax((att - globalmax)*ALPHA) == softmax(att*ALPHA) since the
// global max is a scalar shift (softmax shift-invariant; -inf mask applied
// after). Net: standard causal SDPA with scale 1/sqrt(HD) = 0.125.

#define Bsz 2
#define Tsz 2048
#define Csz 1024
#define Hsz 16
#define HDsz 64

// ---------------------------------------------------------------------------
// f32 tiled GEMM: C[M,N] = A[M,K] @ W[K,N] + bias[N]
// 64x64 tile per block, 256 threads, 4x4 per thread, K-step 16.
// ---------------------------------------------------------------------------
__global__ __launch_bounds__(256) void gemm_bias_f32(
    const float* __restrict__ A, const float* __restrict__ W,
    const float* __restrict__ bias, float* __restrict__ Cout,
    int M, int N, int K) {
  __shared__ float As[16][64];  // [k][m]
  __shared__ float Bs[16][64];  // [k][n]
  const int tid = threadIdx.x;
  const int tx = tid & 15;      // n-dir
  const int ty = tid >> 4;      // m-dir
  const int m0 = blockIdx.y * 64;
  const int n0 = blockIdx.x * 64;

  float acc[4][4] = {};

  for (int k0 = 0; k0 < K; k0 += 16) {
    // A tile: 64 rows x 16 k. thread -> row=tid>>2, k=(tid&3)*4 (float4)
    {
      const int row = tid >> 2;
      const int kk = (tid & 3) * 4;
      const float4 av = *(const float4*)(A + (size_t)(m0 + row) * K + k0 + kk);
      As[kk + 0][row] = av.x;
      As[kk + 1][row] = av.y;
      As[kk + 2][row] = av.z;
      As[kk + 3][row] = av.w;
    }
    // B tile: 16 k x 64 n. thread -> k=tid>>4, n=(tid&15)*4 (float4, coalesced)
    {
      const int kk = tid >> 4;
      const int nn = (tid & 15) * 4;
      const float4 bv = *(const float4*)(W + (size_t)(k0 + kk) * N + n0 + nn);
      *(float4*)&Bs[kk][nn] = bv;
    }
    __syncthreads();
#pragma unroll
    for (int kk = 0; kk < 16; ++kk) {
      float a[4], b[4];
#pragma unroll
      for (int i = 0; i < 4; ++i) a[i] = As[kk][ty * 4 + i];
#pragma unroll
      for (int j = 0; j < 4; ++j) b[j] = Bs[kk][tx * 4 + j];
#pragma unroll
      for (int i = 0; i < 4; ++i)
#pragma unroll
        for (int j = 0; j < 4; ++j) acc[i][j] += a[i] * b[j];
    }
    __syncthreads();
  }

#pragma unroll
  for (int i = 0; i < 4; ++i) {
    const int m = m0 + ty * 4 + i;
    const int n = n0 + tx * 4;
    float4 o;
    o.x = acc[i][0] + bias[n + 0];
    o.y = acc[i][1] + bias[n + 1];
    o.z = acc[i][2] + bias[n + 2];
    o.w = acc[i][3] + bias[n + 3];
    *(float4*)(Cout + (size_t)m * N + n) = o;
  }
}

// ---------------------------------------------------------------------------
// Flash-style causal attention (f32).
// grid: (T/16, B*H); block: 256 threads = 4 waves; wave w handles query rows
// i0 + 4w .. i0 + 4w + 3. K/V tiles of 64 keys staged in LDS (pad 65 -> 2-way
// bank aliasing only, free). Online softmax state per row in registers; o is
// distributed one element per lane (d = lane).
// ---------------------------------------------------------------------------
__global__ __launch_bounds__(256) void attn_causal(
    const float* __restrict__ Q, const float* __restrict__ K,
    const float* __restrict__ V, float* __restrict__ Y) {
  const int bh = blockIdx.y;
  const int b = bh >> 4;
  const int h = bh & 15;
  const int i0 = blockIdx.x * 16;
  const int tid = threadIdx.x;
  const int wave = tid >> 6;
  const int lane = tid & 63;

  __shared__ float Ks[64][65];
  __shared__ float Vs[64][65];
  __shared__ float qs[16][64];

  // load 16 q rows (coalesced float4)
  {
    const int r = tid >> 4;
    const int d4 = (tid & 15) * 4;
    const float4 qv =
        *(const float4*)(Q + ((size_t)b * Tsz + i0 + r) * Csz + h * HDsz + d4);
    *(float4*)&qs[r][d4] = qv;
  }

  float m[4], l[4], o[4];
#pragma unroll
  for (int r = 0; r < 4; ++r) {
    m[r] = -__builtin_inff();
    l[r] = 0.f;
    o[r] = 0.f;
  }

  const int rowBase = i0 + wave * 4;
  const int iMax = i0 + 15;

  for (int j0 = 0; j0 <= iMax; j0 += 64) {
    __syncthreads();  // protect prior-iteration LDS reads
    // stage K,V tile: 64 rows x 64 d
#pragma unroll
    for (int e = 0; e < 4; ++e) {
      const int idx = e * 256 + tid;
      const int row = idx >> 4;
      const int d4 = (idx & 15) * 4;
      const size_t g = ((size_t)b * Tsz + j0 + row) * Csz + h * HDsz + d4;
      const float4 kv = *(const float4*)(K + g);
      Ks[row][d4 + 0] = kv.x;
      Ks[row][d4 + 1] = kv.y;
      Ks[row][d4 + 2] = kv.z;
      Ks[row][d4 + 3] = kv.w;
      const float4 vv = *(const float4*)(V + g);
      Vs[row][d4 + 0] = vv.x;
      Vs[row][d4 + 1] = vv.y;
      Vs[row][d4 + 2] = vv.z;
      Vs[row][d4 + 3] = vv.w;
    }
    __syncthreads();

    // scores for key j = j0 + lane, all 4 rows of this wave
    float s[4] = {0.f, 0.f, 0.f, 0.f};
    for (int d = 0; d < 64; ++d) {
      const float kd = Ks[lane][d];
#pragma unroll
      for (int r = 0; r < 4; ++r) s[r] += kd * qs[wave * 4 + r][d];
    }

    const int j = j0 + lane;
#pragma unroll
    for (int r = 0; r < 4; ++r) {
      const int i = rowBase + r;
      if (j0 > i) continue;  // tile entirely masked for this row
      float sr = (j <= i) ? s[r] * 0.125f : -__builtin_inff();
      // wave-wide max
      float mt = sr;
#pragma unroll
      for (int off = 32; off; off >>= 1) mt = fmaxf(mt, __shfl_xor(mt, off));
      const float mnew = fmaxf(m[r], mt);
      const float alpha = __expf(m[r] - mnew);  // m=-inf first iter -> 0
      const float p = __expf(sr - mnew);        // masked lanes -> exp(-inf)=0
      float ps = p;
#pragma unroll
      for (int off = 32; off; off >>= 1) ps += __shfl_xor(ps, off);
      l[r] = l[r] * alpha + ps;
      m[r] = mnew;
      // o_d = o_d*alpha + sum_j p_j * V[j][d]   (d = lane)
      float od = o[r] * alpha;
      for (int jj = 0; jj < 64; ++jj) {
        const float pj = __shfl(p, jj);
        od += pj * Vs[jj][lane];
      }
      o[r] = od;
    }
  }

  // y[b, i, h*HD + lane]
#pragma unroll
  for (int r = 0; r < 4; ++r) {
    const int i = rowBase + r;
    Y[((size_t)b * Tsz + i) * Csz + h * HDsz + lane] = o[r] / l[r];
  }
}

extern "C" void kernel_launch(void* const* d_in, const int* in_sizes, int n_in,
                              void* d_out, int out_size, void* d_ws,
                              size_t ws_size, hipStream_t stream) {
  const float* query = (const float*)d_in[0];
  const float* key = (const float*)d_in[1];
  const float* value = (const float*)d_in[2];
  // d_in[3] = att_mask (tril causal) -- structure hard-coded in attn kernel
  const float* Wq = (const float*)d_in[4];
  const float* bq = (const float*)d_in[5];
  const float* Wk = (const float*)d_in[6];
  const float* bk = (const float*)d_in[7];
  const float* Wv = (const float*)d_in[8];
  const float* bv = (const float*)d_in[9];
  const float* Wp = (const float*)d_in[10];
  const float* bp = (const float*)d_in[11];
  float* out = (float*)d_out;

  const size_t elems = (size_t)Bsz * Tsz * Csz;  // 4,194,304
  float* ws = (float*)d_ws;
  float* Qb = ws;
  float* Kb = ws + elems;
  float* Vb = ws + 2 * elems;
  float* Yb = ws + 3 * elems;

  const int M = Bsz * Tsz;  // 4096
  dim3 gGrid(Csz / 64, M / 64);  // (16, 64)
  dim3 gBlock(256);

  gemm_bias_f32<<<gGrid, gBlock, 0, stream>>>(query, Wq, bq, Qb, M, Csz, Csz);
  gemm_bias_f32<<<gGrid, gBlock, 0, stream>>>(key, Wk, bk, Kb, M, Csz, Csz);
  gemm_bias_f32<<<gGrid, gBlock, 0, stream>>>(value, Wv, bv, Vb, M, Csz, Csz);

  dim3 aGrid(Tsz / 16, Bsz * Hsz);  // (128, 32)
  attn_causal<<<aGrid, dim3(256), 0, stream>>>(Qb, Kb, Vb, Yb);

  gemm_bias_f32<<<gGrid, gBlock, 0, stream>>>(Yb, Wp, bp, out, M, Csz, Csz);
}

// Round 2
// 713.169 us; speedup vs baseline: 4.6002x; 4.6002x over previous
//
#include <hip/hip_runtime.h>

// B=2, T=2048, C=1024, H=16, HD=64, ALPHA=32
// softmax((att - globalmax)*ALPHA) == softmax(att*ALPHA): global-max shift
// cancels (softmax shift-invariant; -inf mask applied after the shift).
// Net: causal SDPA with scale 1/sqrt(HD)=0.125, done in bf16 MFMA.

#define Bsz 2
#define Tsz 2048
#define Csz 1024
#define Hsz 16
#define HDsz 64

typedef __bf16 bf16;
typedef __bf16 bf16x8 __attribute__((ext_vector_type(8)));
typedef float float4v __attribute__((ext_vector_type(4)));
typedef unsigned short us16;
typedef unsigned short us8 __attribute__((ext_vector_type(8)));

#define MFMA16(a, b, c) __builtin_amdgcn_mfma_f32_16x16x32_bf16(a, b, c, 0, 0, 0)

// ---------------------------------------------------------------------------
// f32 tiled GEMM: C[M,N] = A[M,K] @ W[K,N] + bias[N]; OutT = float or bf16.
// 64x64 tile, 256 threads, 4x4/thread.
// ---------------------------------------------------------------------------
template <typename OutT>
__global__ __launch_bounds__(256) void gemm_bias(
    const float* __restrict__ A, const float* __restrict__ W,
    const float* __restrict__ bias, OutT* __restrict__ Cout,
    int M, int N, int K) {
  __shared__ float As[16][64];  // [k][m]
  __shared__ float Bs[16][64];  // [k][n]
  const int tid = threadIdx.x;
  const int tx = tid & 15;
  const int ty = tid >> 4;
  const int m0 = blockIdx.y * 64;
  const int n0 = blockIdx.x * 64;

  float acc[4][4] = {};

  for (int k0 = 0; k0 < K; k0 += 16) {
    {
      const int row = tid >> 2;
      const int kk = (tid & 3) * 4;
      const float4 av = *(const float4*)(A + (size_t)(m0 + row) * K + k0 + kk);
      As[kk + 0][row] = av.x;
      As[kk + 1][row] = av.y;
      As[kk + 2][row] = av.z;
      As[kk + 3][row] = av.w;
    }
    {
      const int kk = tid >> 4;
      const int nn = (tid & 15) * 4;
      *(float4*)&Bs[kk][nn] =
          *(const float4*)(W + (size_t)(k0 + kk) * N + n0 + nn);
    }
    __syncthreads();
#pragma unroll
    for (int kk = 0; kk < 16; ++kk) {
      float a[4], b[4];
#pragma unroll
      for (int i = 0; i < 4; ++i) a[i] = As[kk][ty * 4 + i];
#pragma unroll
      for (int j = 0; j < 4; ++j) b[j] = Bs[kk][tx * 4 + j];
#pragma unroll
      for (int i = 0; i < 4; ++i)
#pragma unroll
        for (int j = 0; j < 4; ++j) acc[i][j] += a[i] * b[j];
    }
    __syncthreads();
  }

#pragma unroll
  for (int i = 0; i < 4; ++i) {
    const int mm = m0 + ty * 4 + i;
    const int nn = n0 + tx * 4;
    float o[4];
#pragma unroll
    for (int j = 0; j < 4; ++j) o[j] = acc[i][j] + bias[nn + j];
    if constexpr (sizeof(OutT) == 2) {
      union {
        bf16 h[4];
        uint2 u;
      } pk;
#pragma unroll
      for (int j = 0; j < 4; ++j) pk.h[j] = (bf16)o[j];
      *(uint2*)((bf16*)Cout + (size_t)mm * N + nn) = pk.u;
    } else {
      float4 ov;
      ov.x = o[0]; ov.y = o[1]; ov.z = o[2]; ov.w = o[3];
      *(float4*)((float*)Cout + (size_t)mm * N + nn) = ov;
    }
  }
}

// ---------------------------------------------------------------------------
// V [B,T,C](bf16, per-head cols) -> Vt [B*H, HD, T] (bf16). 64x64 LDS tile
// with XOR swizzle (conflict-free-ish), bitwise copies only.
// ---------------------------------------------------------------------------
__global__ __launch_bounds__(256) void transpose_v(const us16* __restrict__ V,
                                                   us16* __restrict__ Vt) {
  __shared__ us16 Ts[64][64];
  const int bh = blockIdx.y;
  const int b = bh >> 4, h = bh & 15;
  const int t0 = blockIdx.x * 64;
  const int tid = threadIdx.x;
#pragma unroll
  for (int it = 0; it < 2; ++it) {
    const int c = it * 256 + tid;
    const int r = c >> 3, cb = c & 7;
    const us8 v =
        *(const us8*)&V[(size_t)(b * Tsz + t0 + r) * Csz + h * HDsz + cb * 8];
    *(us8*)&Ts[r][(cb ^ (r & 7)) * 8] = v;
  }
  __syncthreads();
#pragma unroll
  for (int it = 0; it < 2; ++it) {
    const int d = tid & 63;
    const int tb = (tid >> 6) + it * 4;
    us8 o;
#pragma unroll
    for (int j = 0; j < 8; ++j) {
      o[j] = Ts[tb * 8 + j][(((d >> 3) ^ j) * 8) + (d & 7)];
    }
    *(us8*)&Vt[((size_t)bh * HDsz + d) * Tsz + t0 + tb * 8] = o;
  }
}

// ---------------------------------------------------------------------------
// Flash attention, bf16 MFMA. grid (T/64, B*H), 256 thr = 4 waves.
// Wave w owns q rows i0+w*16 .. +15. Per 64-key tile: QK^T (8 MFMA),
// online softmax in C-layout (row=quad*4+reg, col=lane&15), P -> per-wave LDS
// in A-frag-linear order, PV (8 MFMA) into O frags.
// ---------------------------------------------------------------------------
__global__ __launch_bounds__(256) void attn_mfma(const bf16* __restrict__ Q,
                                                 const bf16* __restrict__ K,
                                                 const bf16* __restrict__ Vt,
                                                 float* __restrict__ Y) {
  __shared__ bf16 Ks[64][80];   // keys x d (pad 80 keeps 16B align)
  __shared__ bf16 Vts[64][80];  // d x keys
  __shared__ bf16 Ps[4][1024];  // per-wave P in A-frag-linear order

  const int bh = blockIdx.y;
  const int b = bh >> 4, h = bh & 15;
  const int i0 = blockIdx.x * 64;
  const int tid = threadIdx.x;
  const int wave = tid >> 6, lane = tid & 63;
  const int l15 = lane & 15, quad = lane >> 4;

  // Q A-frags, held in registers for the whole kernel
  bf16x8 qf0, qf1;
  {
    const bf16* qp =
        Q + ((size_t)b * Tsz + i0 + wave * 16 + l15) * Csz + h * HDsz + quad * 8;
    qf0 = *(const bf16x8*)qp;
    qf1 = *(const bf16x8*)(qp + 32);
  }

  float4v Of[4];
  float m[4], l[4];
#pragma unroll
  for (int nc = 0; nc < 4; ++nc) Of[nc] = (float4v){0.f, 0.f, 0.f, 0.f};
#pragma unroll
  for (int r = 0; r < 4; ++r) {
    m[r] = -1e30f;
    l[r] = 0.f;
  }

  for (int j0 = 0; j0 <= i0; j0 += 64) {
    __syncthreads();
// stage K tile (keys x d) and Vt tile (d x keys), 16B chunks
#pragma unroll
    for (int it = 0; it < 2; ++it) {
      const int c = it * 256 + tid;
      const int row = c >> 3, cb = c & 7;
      *(bf16x8*)&Ks[row][cb * 8] = *(const bf16x8*)&K[(size_t)(b * Tsz + j0 + row) * Csz + h * HDsz + cb * 8];
      *(bf16x8*)&Vts[row][cb * 8] = *(const bf16x8*)&Vt[((size_t)bh * HDsz + row) * Tsz + j0 + cb * 8];
    }
    __syncthreads();

    // S = Q K^T  (C-layout: row=quad*4+r, col=l15 within 16-chunk nc)
    float4v S[4];
#pragma unroll
    for (int nc = 0; nc < 4; ++nc) {
      const bf16x8 k0 = *(const bf16x8*)&Ks[nc * 16 + l15][quad * 8];
      const bf16x8 k1 = *(const bf16x8*)&Ks[nc * 16 + l15][32 + quad * 8];
      float4v acc = (float4v){0.f, 0.f, 0.f, 0.f};
      acc = MFMA16(qf0, k0, acc);
      acc = MFMA16(qf1, k1, acc);
      S[nc] = acc;
    }

    const bool diag = (j0 == i0);
    const int qlb = wave * 16 + quad * 4;  // block-local q row base
#pragma unroll
    for (int nc = 0; nc < 4; ++nc) {
#pragma unroll
      for (int r = 0; r < 4; ++r) {
        float s = S[nc][r] * 0.125f;
        if (diag && (nc * 16 + l15) > (qlb + r)) s = -1e30f;
        S[nc][r] = s;
      }
    }

// online softmax, per C-row r
#pragma unroll
    for (int r = 0; r < 4; ++r) {
      float mt = fmaxf(fmaxf(S[0][r], S[1][r]), fmaxf(S[2][r], S[3][r]));
#pragma unroll
      for (int off = 1; off <= 8; off <<= 1) mt = fmaxf(mt, __shfl_xor(mt, off));
      const float mn = fmaxf(m[r], mt);
      const float al = __expf(m[r] - mn);
      float ps = 0.f;
#pragma unroll
      for (int nc = 0; nc < 4; ++nc) {
        const float p = __expf(S[nc][r] - mn);
        S[nc][r] = p;
        ps += p;
      }
#pragma unroll
      for (int off = 1; off <= 8; off <<= 1) ps += __shfl_xor(ps, off);
      l[r] = l[r] * al + ps;
      m[r] = mn;
#pragma unroll
      for (int nc = 0; nc < 4; ++nc) Of[nc][r] *= al;
    }

// write P (bf16) into per-wave LDS, A-frag-linear: element j of lane L,
// chunk kc holds P[q=L&15][key=kc*32+(L>>4)*8+j]
#pragma unroll
    for (int nc = 0; nc < 4; ++nc) {
      const int keyl = nc * 16 + l15;
      const int kc = keyl >> 5;
      const int jj = keyl & 7;
      const int Lhi = ((keyl >> 3) & 3) * 16;
#pragma unroll
      for (int r = 0; r < 4; ++r) {
        const int L = Lhi + quad * 4 + r;
        Ps[wave][kc * 512 + L * 8 + jj] = (bf16)S[nc][r];
      }
    }

    // PV: O[q][d] += P[q][key] * Vt[d][key]
    const bf16x8 pf0 = *(const bf16x8*)&Ps[wave][0 * 512 + lane * 8];
    const bf16x8 pf1 = *(const bf16x8*)&Ps[wave][1 * 512 + lane * 8];
#pragma unroll
    for (int nc = 0; nc < 4; ++nc) {
      const bf16x8 v0 = *(const bf16x8*)&Vts[nc * 16 + l15][quad * 8];
      const bf16x8 v1 = *(const bf16x8*)&Vts[nc * 16 + l15][32 + quad * 8];
      Of[nc] = MFMA16(pf0, v0, Of[nc]);
      Of[nc] = MFMA16(pf1, v1, Of[nc]);
    }
  }

// epilogue: Y = O / l  (f32, feeds the f32 out-projection GEMM)
#pragma unroll
  for (int nc = 0; nc < 4; ++nc) {
#pragma unroll
    for (int r = 0; r < 4; ++r) {
      const size_t row = (size_t)b * Tsz + i0 + wave * 16 + quad * 4 + r;
      Y[row * Csz + h * HDsz + nc * 16 + l15] = Of[nc][r] / l[r];
    }
  }
}

extern "C" void kernel_launch(void* const* d_in, const int* in_sizes, int n_in,
                              void* d_out, int out_size, void* d_ws,
                              size_t ws_size, hipStream_t stream) {
  const float* query = (const float*)d_in[0];
  const float* key = (const float*)d_in[1];
  const float* value = (const float*)d_in[2];
  // d_in[3] = att_mask (tril causal) -- hard-coded in attn kernel
  const float* Wq = (const float*)d_in[4];
  const float* bq = (const float*)d_in[5];
  const float* Wk = (const float*)d_in[6];
  const float* bk = (const float*)d_in[7];
  const float* Wv = (const float*)d_in[8];
  const float* bv = (const float*)d_in[9];
  const float* Wp = (const float*)d_in[10];
  const float* bp = (const float*)d_in[11];
  float* out = (float*)d_out;

  char* ws = (char*)d_ws;
  bf16* Qb = (bf16*)(ws);                       // 8 MB
  bf16* Kb = (bf16*)(ws + (8u << 20));          // 8 MB
  bf16* Vb = (bf16*)(ws + (16u << 20));         // 8 MB
  bf16* Vtb = (bf16*)(ws + (24u << 20));        // 8 MB
  float* Yb = (float*)(ws + (32u << 20));       // 16 MB

  const int M = Bsz * Tsz;       // 4096
  dim3 gGrid(Csz / 64, M / 64);  // (16, 64)

  gemm_bias<bf16><<<gGrid, dim3(256), 0, stream>>>(query, Wq, bq, Qb, M, Csz, Csz);
  gemm_bias<bf16><<<gGrid, dim3(256), 0, stream>>>(key, Wk, bk, Kb, M, Csz, Csz);
  gemm_bias<bf16><<<gGrid, dim3(256), 0, stream>>>(value, Wv, bv, Vb, M, Csz, Csz);

  transpose_v<<<dim3(Tsz / 64, Bsz * Hsz), dim3(256), 0, stream>>>(
      (const us16*)Vb, (us16*)Vtb);

  attn_mfma<<<dim3(Tsz / 64, Bsz * Hsz), dim3(256), 0, stream>>>(Qb, Kb, Vtb, Yb);

  gemm_bias<float><<<gGrid, dim3(256), 0, stream>>>(Yb, Wp, bp, out, M, Csz, Csz);
}

// Round 3
// 318.771 us; speedup vs baseline: 10.2918x; 2.2372x over previous
//
#include <hip/hip_runtime.h>

// B=2, T=2048, C=1024, H=16, HD=64, ALPHA=32
// softmax((att - globalmax)*ALPHA) == softmax(att*ALPHA): the global-max shift
// cancels (softmax shift-invariant; -inf mask applied after the shift).
// Net: causal SDPA with scale 1/sqrt(HD)=0.125, all matmuls in bf16 MFMA.

#define Bsz 2
#define Tsz 2048
#define Csz 1024
#define Hsz 16
#define HDsz 64

typedef __bf16 bf16;
typedef __bf16 bf16x8 __attribute__((ext_vector_type(8)));
typedef float float4v __attribute__((ext_vector_type(4)));
typedef unsigned short us16;
typedef unsigned short us8 __attribute__((ext_vector_type(8)));

#define MFMA16(a, b, c) __builtin_amdgcn_mfma_f32_16x16x32_bf16(a, b, c, 0, 0, 0)

// async global->LDS, 16B per lane; LDS dest must be wave-uniform base + lane*16
#define GLOAD_LDS16(gptr, lptr)                                      \
  __builtin_amdgcn_global_load_lds(                                  \
      (const __attribute__((address_space(1))) void*)(gptr),         \
      (__attribute__((address_space(3))) void*)(lptr), 16, 0, 0)

// ---------------------------------------------------------------------------
// cast f32 -> bf16, 3 tensors batched via grid.z, 8 elems/thread
// ---------------------------------------------------------------------------
__global__ __launch_bounds__(256) void cast3_bf16(
    const float* __restrict__ q, const float* __restrict__ k,
    const float* __restrict__ v, bf16* __restrict__ oq,
    bf16* __restrict__ ok, bf16* __restrict__ ov) {
  const int z = blockIdx.z;
  const float* src = z == 0 ? q : (z == 1 ? k : v);
  bf16* dst = z == 0 ? oq : (z == 1 ? ok : ov);
  const size_t i = ((size_t)blockIdx.x * 256 + threadIdx.x) * 8;
  const float4 a = *(const float4*)(src + i);
  const float4 b = *(const float4*)(src + i + 4);
  bf16x8 o;
  o[0] = (bf16)a.x; o[1] = (bf16)a.y; o[2] = (bf16)a.z; o[3] = (bf16)a.w;
  o[4] = (bf16)b.x; o[5] = (bf16)b.y; o[6] = (bf16)b.z; o[7] = (bf16)b.w;
  *(bf16x8*)(dst + i) = o;
}

// ---------------------------------------------------------------------------
// weight transpose+cast: W[K,N] f32 -> WT[N,K] bf16; grid.z selects Wq/Wk/Wv/Wp
// ---------------------------------------------------------------------------
__global__ __launch_bounds__(256) void wtrans_bf16(
    const float* __restrict__ Wq, const float* __restrict__ Wk,
    const float* __restrict__ Wv, const float* __restrict__ Wp,
    bf16* __restrict__ WT) {
  const int z = blockIdx.z;
  const float* W = z == 0 ? Wq : (z == 1 ? Wk : (z == 2 ? Wv : Wp));
  bf16* out = WT + (size_t)z * (Csz * Csz);
  __shared__ float Ts[64][68];  // 68: 16B-aligned rows, banks step 4 on cols
  const int k0 = blockIdx.y * 64, n0 = blockIdx.x * 64;
  const int tid = threadIdx.x;
#pragma unroll
  for (int it = 0; it < 4; ++it) {
    const int idx = it * 256 + tid;
    const int r = idx >> 4, c4 = (idx & 15) * 4;
    *(float4*)&Ts[r][c4] = *(const float4*)(W + (size_t)(k0 + r) * Csz + n0 + c4);
  }
  __syncthreads();
#pragma unroll
  for (int it = 0; it < 2; ++it) {
    const int idx = it * 256 + tid;
    const int n = idx & 63, k8 = (idx >> 6) * 8;
    bf16x8 o;
#pragma unroll
    for (int j = 0; j < 8; ++j) o[j] = (bf16)Ts[k8 + j][n];
    *(bf16x8*)(out + (size_t)(n0 + n) * Csz + k0 + k8) = o;
  }
}

// ---------------------------------------------------------------------------
// bf16 MFMA GEMM (m97 structure): C[M,N] = A[M,K] @ Bt[N,K]^T + bias
// 128x128 tile, BK=32, 256 thr = 4 waves (2x2), wave does 4x4 16x16 tiles.
// grid.z batches up to 3 (A,bias,C selected; Bt strided by z*N*K).
// ---------------------------------------------------------------------------
template <typename OutT>
__global__ __launch_bounds__(256) void gemm_mfma(
    const bf16* __restrict__ A0, const bf16* __restrict__ A1,
    const bf16* __restrict__ A2, const bf16* __restrict__ Wt,
    const float* __restrict__ b0, const float* __restrict__ b1,
    const float* __restrict__ b2, OutT* __restrict__ C0,
    OutT* __restrict__ C1, OutT* __restrict__ C2, int M, int N, int K) {
  const int z = blockIdx.z;
  const bf16* A = z == 0 ? A0 : (z == 1 ? A1 : A2);
  const float* bias = z == 0 ? b0 : (z == 1 ? b1 : b2);
  OutT* C = z == 0 ? C0 : (z == 1 ? C1 : C2);
  const bf16* Bt = Wt + (size_t)z * N * K;

  __shared__ bf16 As[128 * 32];
  __shared__ bf16 Bs[128 * 32];
  const int tid = threadIdx.x;
  const int wave = tid >> 6, lane = tid & 63;
  const int l15 = lane & 15, quad = lane >> 4;
  const int m0 = blockIdx.y * 128, n0 = blockIdx.x * 128;
  const int wm = (wave >> 1) * 64, wn = (wave & 1) * 64;
  const int srow = tid >> 2, schunk = tid & 3;

  float4v acc[4][4];
#pragma unroll
  for (int i = 0; i < 4; ++i)
#pragma unroll
    for (int j = 0; j < 4; ++j) acc[i][j] = (float4v){0.f, 0.f, 0.f, 0.f};

  for (int k0 = 0; k0 < K; k0 += 32) {
    __syncthreads();  // protect prior-iteration LDS reads
#pragma unroll
    for (int p = 0; p < 2; ++p) {
      const int row = p * 64 + srow;
      GLOAD_LDS16(A + (size_t)(m0 + row) * K + k0 + schunk * 8,
                  &As[(p * 256 + tid) * 8]);
      GLOAD_LDS16(Bt + (size_t)(n0 + row) * K + k0 + schunk * 8,
                  &Bs[(p * 256 + tid) * 8]);
    }
    __syncthreads();  // vmcnt(0) drained here

    bf16x8 af[4], bfr[4];
#pragma unroll
    for (int i = 0; i < 4; ++i)
      af[i] = *(const bf16x8*)&As[(wm + i * 16 + l15) * 32 + quad * 8];
#pragma unroll
    for (int j = 0; j < 4; ++j)
      bfr[j] = *(const bf16x8*)&Bs[(wn + j * 16 + l15) * 32 + quad * 8];
#pragma unroll
    for (int i = 0; i < 4; ++i)
#pragma unroll
      for (int j = 0; j < 4; ++j)
        acc[i][j] = MFMA16(af[i], bfr[j], acc[i][j]);
  }

  // C-layout: D[m=quad*4+r][n=l15] per 16x16 tile (m89-verified map)
  const int omb = m0 + wm + quad * 4;
  const int onb = n0 + wn + l15;
#pragma unroll
  for (int j = 0; j < 4; ++j) {
    const float bj = bias[onb + j * 16];
#pragma unroll
    for (int i = 0; i < 4; ++i) {
#pragma unroll
      for (int r = 0; r < 4; ++r) {
        const float v = acc[i][j][r] + bj;
        const size_t off = (size_t)(omb + i * 16 + r) * N + onb + j * 16;
        if constexpr (sizeof(OutT) == 2)
          C[off] = (OutT)v;
        else
          C[off] = v;
      }
    }
  }
}

// ---------------------------------------------------------------------------
// V [B,T,C](bf16) -> Vt [B*H, HD, T] (bf16), XOR-swizzled LDS transpose
// ---------------------------------------------------------------------------
__global__ __launch_bounds__(256) void transpose_v(const us16* __restrict__ V,
                                                   us16* __restrict__ Vt) {
  __shared__ us16 Ts[64][64];
  const int bh = blockIdx.y;
  const int b = bh >> 4, h = bh & 15;
  const int t0 = blockIdx.x * 64;
  const int tid = threadIdx.x;
#pragma unroll
  for (int it = 0; it < 2; ++it) {
    const int c = it * 256 + tid;
    const int r = c >> 3, cb = c & 7;
    const us8 v =
        *(const us8*)&V[(size_t)(b * Tsz + t0 + r) * Csz + h * HDsz + cb * 8];
    *(us8*)&Ts[r][(cb ^ (r & 7)) * 8] = v;
  }
  __syncthreads();
#pragma unroll
  for (int it = 0; it < 2; ++it) {
    const int d = tid & 63;
    const int tb = (tid >> 6) + it * 4;
    us8 o;
#pragma unroll
    for (int j = 0; j < 8; ++j)
      o[j] = Ts[tb * 8 + j][(((d >> 3) ^ j) * 8) + (d & 7)];
    *(us8*)&Vt[((size_t)bh * HDsz + d) * Tsz + t0 + tb * 8] = o;
  }
}

// ---------------------------------------------------------------------------
// Flash attention, bf16 MFMA (verified round 2); epilogue now emits bf16.
// ---------------------------------------------------------------------------
__global__ __launch_bounds__(256) void attn_mfma(const bf16* __restrict__ Q,
                                                 const bf16* __restrict__ K,
                                                 const bf16* __restrict__ Vt,
                                                 bf16* __restrict__ Y) {
  __shared__ bf16 Ks[64][80];
  __shared__ bf16 Vts[64][80];
  __shared__ bf16 Ps[4][1024];

  const int bh = blockIdx.y;
  const int b = bh >> 4, h = bh & 15;
  const int i0 = blockIdx.x * 64;
  const int tid = threadIdx.x;
  const int wave = tid >> 6, lane = tid & 63;
  const int l15 = lane & 15, quad = lane >> 4;

  bf16x8 qf0, qf1;
  {
    const bf16* qp =
        Q + ((size_t)b * Tsz + i0 + wave * 16 + l15) * Csz + h * HDsz + quad * 8;
    qf0 = *(const bf16x8*)qp;
    qf1 = *(const bf16x8*)(qp + 32);
  }

  float4v Of[4];
  float m[4], l[4];
#pragma unroll
  for (int nc = 0; nc < 4; ++nc) Of[nc] = (float4v){0.f, 0.f, 0.f, 0.f};
#pragma unroll
  for (int r = 0; r < 4; ++r) {
    m[r] = -1e30f;
    l[r] = 0.f;
  }

  for (int j0 = 0; j0 <= i0; j0 += 64) {
    __syncthreads();
#pragma unroll
    for (int it = 0; it < 2; ++it) {
      const int c = it * 256 + tid;
      const int row = c >> 3, cb = c & 7;
      *(bf16x8*)&Ks[row][cb * 8] =
          *(const bf16x8*)&K[(size_t)(b * Tsz + j0 + row) * Csz + h * HDsz + cb * 8];
      *(bf16x8*)&Vts[row][cb * 8] =
          *(const bf16x8*)&Vt[((size_t)bh * HDsz + row) * Tsz + j0 + cb * 8];
    }
    __syncthreads();

    float4v S[4];
#pragma unroll
    for (int nc = 0; nc < 4; ++nc) {
      const bf16x8 k0 = *(const bf16x8*)&Ks[nc * 16 + l15][quad * 8];
      const bf16x8 k1 = *(const bf16x8*)&Ks[nc * 16 + l15][32 + quad * 8];
      float4v acc = (float4v){0.f, 0.f, 0.f, 0.f};
      acc = MFMA16(qf0, k0, acc);
      acc = MFMA16(qf1, k1, acc);
      S[nc] = acc;
    }

    const bool diag = (j0 == i0);
    const int qlb = wave * 16 + quad * 4;
#pragma unroll
    for (int nc = 0; nc < 4; ++nc) {
#pragma unroll
      for (int r = 0; r < 4; ++r) {
        float s = S[nc][r] * 0.125f;
        if (diag && (nc * 16 + l15) > (qlb + r)) s = -1e30f;
        S[nc][r] = s;
      }
    }

#pragma unroll
    for (int r = 0; r < 4; ++r) {
      float mt = fmaxf(fmaxf(S[0][r], S[1][r]), fmaxf(S[2][r], S[3][r]));
#pragma unroll
      for (int off = 1; off <= 8; off <<= 1) mt = fmaxf(mt, __shfl_xor(mt, off));
      const float mn = fmaxf(m[r], mt);
      const float al = __expf(m[r] - mn);
      float ps = 0.f;
#pragma unroll
      for (int nc = 0; nc < 4; ++nc) {
        const float p = __expf(S[nc][r] - mn);
        S[nc][r] = p;
        ps += p;
      }
#pragma unroll
      for (int off = 1; off <= 8; off <<= 1) ps += __shfl_xor(ps, off);
      l[r] = l[r] * al + ps;
      m[r] = mn;
#pragma unroll
      for (int nc = 0; nc < 4; ++nc) Of[nc][r] *= al;
    }

#pragma unroll
    for (int nc = 0; nc < 4; ++nc) {
      const int keyl = nc * 16 + l15;
      const int kc = keyl >> 5;
      const int jj = keyl & 7;
      const int Lhi = ((keyl >> 3) & 3) * 16;
#pragma unroll
      for (int r = 0; r < 4; ++r) {
        const int L = Lhi + quad * 4 + r;
        Ps[wave][kc * 512 + L * 8 + jj] = (bf16)S[nc][r];
      }
    }

    const bf16x8 pf0 = *(const bf16x8*)&Ps[wave][0 * 512 + lane * 8];
    const bf16x8 pf1 = *(const bf16x8*)&Ps[wave][1 * 512 + lane * 8];
#pragma unroll
    for (int nc = 0; nc < 4; ++nc) {
      const bf16x8 v0 = *(const bf16x8*)&Vts[nc * 16 + l15][quad * 8];
      const bf16x8 v1 = *(const bf16x8*)&Vts[nc * 16 + l15][32 + quad * 8];
      Of[nc] = MFMA16(pf0, v0, Of[nc]);
      Of[nc] = MFMA16(pf1, v1, Of[nc]);
    }
  }

#pragma unroll
  for (int nc = 0; nc < 4; ++nc) {
#pragma unroll
    for (int r = 0; r < 4; ++r) {
      const size_t row = (size_t)b * Tsz + i0 + wave * 16 + quad * 4 + r;
      Y[row * Csz + h * HDsz + nc * 16 + l15] = (bf16)(Of[nc][r] / l[r]);
    }
  }
}

extern "C" void kernel_launch(void* const* d_in, const int* in_sizes, int n_in,
                              void* d_out, int out_size, void* d_ws,
                              size_t ws_size, hipStream_t stream) {
  const float* query = (const float*)d_in[0];
  const float* key = (const float*)d_in[1];
  const float* value = (const float*)d_in[2];
  // d_in[3] = att_mask (tril causal) -- hard-coded in attn kernel
  const float* Wq = (const float*)d_in[4];
  const float* bq = (const float*)d_in[5];
  const float* Wk = (const float*)d_in[6];
  const float* bk = (const float*)d_in[7];
  const float* Wv = (const float*)d_in[8];
  const float* bv = (const float*)d_in[9];
  const float* Wp = (const float*)d_in[10];
  const float* bp = (const float*)d_in[11];
  float* out = (float*)d_out;

  // workspace map (<=48MB) + d_out (16MB) doubles as cast scratch:
  //   ws[ 0.. 8): WT[4]  (Wq,Wk,Wv,Wp transposed, bf16 [N,K], 2MB each)
  //   ws[ 8..16): vc (cast V)  -> later reused as Yb (attn out, bf16)
  //   ws[16..24): Qp   ws[24..32): Kp   ws[32..40): Vp   ws[40..48): Vt
  //   d_out[0..8): qc (cast Q)   d_out[8..16): kc (cast K)  (dead before
  //   final GEMM overwrites d_out)
  char* ws = (char*)d_ws;
  bf16* WT = (bf16*)(ws);
  bf16* vc = (bf16*)(ws + (8u << 20));
  bf16* Qp = (bf16*)(ws + (16u << 20));
  bf16* Kp = (bf16*)(ws + (24u << 20));
  bf16* Vp = (bf16*)(ws + (32u << 20));
  bf16* Vt = (bf16*)(ws + (40u << 20));
  bf16* Yb = vc;
  bf16* qc = (bf16*)d_out;
  bf16* kc = (bf16*)((char*)d_out + (8u << 20));

  const int M = Bsz * Tsz;  // 4096

  // 1) cast inputs to bf16
  cast3_bf16<<<dim3((M * Csz) / (256 * 8), 1, 3), dim3(256), 0, stream>>>(
      query, key, value, qc, kc, vc);
  // 2) transpose+cast weights
  wtrans_bf16<<<dim3(16, 16, 4), dim3(256), 0, stream>>>(Wq, Wk, Wv, Wp, WT);
  // 3) batched QKV projection (768 blocks = 3/CU)
  gemm_mfma<bf16><<<dim3(Csz / 128, M / 128, 3), dim3(256), 0, stream>>>(
      qc, kc, vc, WT, bq, bk, bv, Qp, Kp, Vp, M, Csz, Csz);
  // 4) V -> Vt [B*H, HD, T]
  transpose_v<<<dim3(Tsz / 64, Bsz * Hsz), dim3(256), 0, stream>>>(
      (const us16*)Vp, (us16*)Vt);
  // 5) flash attention (writes bf16 into Yb = old vc slot)
  attn_mfma<<<dim3(Tsz / 64, Bsz * Hsz), dim3(256), 0, stream>>>(Qp, Kp, Vt, Yb);
  // 6) output projection (f32 out into d_out)
  gemm_mfma<float><<<dim3(Csz / 128, M / 128, 1), dim3(256), 0, stream>>>(
      Yb, Yb, Yb, WT + 3u * (Csz * Csz), bp, bp, bp, out, out, out, M, Csz,
      Csz);
}

// Round 4
// 315.994 us; speedup vs baseline: 10.3822x; 1.0088x over previous
//
#include <hip/hip_runtime.h>

// B=2, T=2048, C=1024, H=16, HD=64, ALPHA=32
// softmax((att - globalmax)*ALPHA) == softmax(att*ALPHA): the global-max shift
// cancels (softmax shift-invariant; -inf mask applied after the shift).
// Net: causal SDPA with scale 1/sqrt(HD)=0.125, all matmuls in bf16 MFMA.

#define Bsz 2
#define Tsz 2048
#define Csz 1024
#define Hsz 16
#define HDsz 64

typedef __bf16 bf16;
typedef __bf16 bf16x8 __attribute__((ext_vector_type(8)));
typedef float float4v __attribute__((ext_vector_type(4)));

#define MFMA16(a, b, c) __builtin_amdgcn_mfma_f32_16x16x32_bf16(a, b, c, 0, 0, 0)

// async global->LDS, 16B per lane; LDS dest must be lane-linear within a wave
#define GLOAD_LDS16(gptr, lptr)                                      \
  __builtin_amdgcn_global_load_lds(                                  \
      (const __attribute__((address_space(1))) void*)(gptr),         \
      (__attribute__((address_space(3))) void*)(lptr), 16, 0, 0)

// ---------------------------------------------------------------------------
// cast f32 -> bf16, 3 tensors batched via grid.z, 8 elems/thread
// ---------------------------------------------------------------------------
__global__ __launch_bounds__(256) void cast3_bf16(
    const float* __restrict__ q, const float* __restrict__ k,
    const float* __restrict__ v, bf16* __restrict__ oq,
    bf16* __restrict__ ok, bf16* __restrict__ ov) {
  const int z = blockIdx.z;
  const float* src = z == 0 ? q : (z == 1 ? k : v);
  bf16* dst = z == 0 ? oq : (z == 1 ? ok : ov);
  const size_t i = ((size_t)blockIdx.x * 256 + threadIdx.x) * 8;
  const float4 a = *(const float4*)(src + i);
  const float4 b = *(const float4*)(src + i + 4);
  bf16x8 o;
  o[0] = (bf16)a.x; o[1] = (bf16)a.y; o[2] = (bf16)a.z; o[3] = (bf16)a.w;
  o[4] = (bf16)b.x; o[5] = (bf16)b.y; o[6] = (bf16)b.z; o[7] = (bf16)b.w;
  *(bf16x8*)(dst + i) = o;
}

// ---------------------------------------------------------------------------
// weight transpose+cast: W[K,N] f32 -> WT[N,K] bf16; grid.z selects Wq/Wk/Wv/Wp
// ---------------------------------------------------------------------------
__global__ __launch_bounds__(256) void wtrans_bf16(
    const float* __restrict__ Wq, const float* __restrict__ Wk,
    const float* __restrict__ Wv, const float* __restrict__ Wp,
    bf16* __restrict__ WT) {
  const int z = blockIdx.z;
  const float* W = z == 0 ? Wq : (z == 1 ? Wk : (z == 2 ? Wv : Wp));
  bf16* out = WT + (size_t)z * (Csz * Csz);
  __shared__ float Ts[64][68];
  const int k0 = blockIdx.y * 64, n0 = blockIdx.x * 64;
  const int tid = threadIdx.x;
#pragma unroll
  for (int it = 0; it < 4; ++it) {
    const int idx = it * 256 + tid;
    const int r = idx >> 4, c4 = (idx & 15) * 4;
    *(float4*)&Ts[r][c4] = *(const float4*)(W + (size_t)(k0 + r) * Csz + n0 + c4);
  }
  __syncthreads();
#pragma unroll
  for (int it = 0; it < 2; ++it) {
    const int idx = it * 256 + tid;
    const int n = idx & 63, k8 = (idx >> 6) * 8;
    bf16x8 o;
#pragma unroll
    for (int j = 0; j < 8; ++j) o[j] = (bf16)Ts[k8 + j][n];
    *(bf16x8*)(out + (size_t)(n0 + n) * Csz + k0 + k8) = o;
  }
}

// ---------------------------------------------------------------------------
// bf16 MFMA GEMM (m97 structure): C[M,N] = A[M,K] @ Bt[N,K]^T + bias
// 128x128 tile, BK=32, 256 thr = 4 waves (2x2), wave does 4x4 16x16 tiles.
// grid.z batches up to 3. VTR: z==2 writes output in Vt[B*H, HD, T] layout
// (fused V-transpose; Vt row index == b*1024 + n, col == t).
// ---------------------------------------------------------------------------
template <typename OutT, bool VTR>
__global__ __launch_bounds__(256) void gemm_mfma(
    const bf16* __restrict__ A0, const bf16* __restrict__ A1,
    const bf16* __restrict__ A2, const bf16* __restrict__ Wt,
    const float* __restrict__ b0, const float* __restrict__ b1,
    const float* __restrict__ b2, OutT* __restrict__ C0,
    OutT* __restrict__ C1, OutT* __restrict__ C2, int M, int N, int K) {
  const int z = blockIdx.z;
  const bf16* A = z == 0 ? A0 : (z == 1 ? A1 : A2);
  const float* bias = z == 0 ? b0 : (z == 1 ? b1 : b2);
  OutT* C = z == 0 ? C0 : (z == 1 ? C1 : C2);
  const bf16* Bt = Wt + (size_t)z * N * K;

  __shared__ bf16 As[128 * 32];
  __shared__ bf16 Bs[128 * 32];
  const int tid = threadIdx.x;
  const int wave = tid >> 6, lane = tid & 63;
  const int l15 = lane & 15, quad = lane >> 4;
  const int m0 = blockIdx.y * 128, n0 = blockIdx.x * 128;
  const int wm = (wave >> 1) * 64, wn = (wave & 1) * 64;
  const int srow = tid >> 2, schunk = tid & 3;

  float4v acc[4][4];
#pragma unroll
  for (int i = 0; i < 4; ++i)
#pragma unroll
    for (int j = 0; j < 4; ++j) acc[i][j] = (float4v){0.f, 0.f, 0.f, 0.f};

  for (int k0 = 0; k0 < K; k0 += 32) {
    __syncthreads();
#pragma unroll
    for (int p = 0; p < 2; ++p) {
      const int row = p * 64 + srow;
      GLOAD_LDS16(A + (size_t)(m0 + row) * K + k0 + schunk * 8,
                  &As[(p * 256 + tid) * 8]);
      GLOAD_LDS16(Bt + (size_t)(n0 + row) * K + k0 + schunk * 8,
                  &Bs[(p * 256 + tid) * 8]);
    }
    __syncthreads();

    bf16x8 af[4], bfr[4];
#pragma unroll
    for (int i = 0; i < 4; ++i)
      af[i] = *(const bf16x8*)&As[(wm + i * 16 + l15) * 32 + quad * 8];
#pragma unroll
    for (int j = 0; j < 4; ++j)
      bfr[j] = *(const bf16x8*)&Bs[(wn + j * 16 + l15) * 32 + quad * 8];
#pragma unroll
    for (int i = 0; i < 4; ++i)
#pragma unroll
      for (int j = 0; j < 4; ++j)
        acc[i][j] = MFMA16(af[i], bfr[j], acc[i][j]);
  }

  // C-layout per 16x16 tile: D[m=quad*4+r][n=l15] (m89-verified)
  const int omb = m0 + wm + quad * 4;
  const int onb = n0 + wn + l15;
  if (VTR && z == 2) {
    // fused V transpose: Vt[(b*1024 + n)][t] = v
#pragma unroll
    for (int j = 0; j < 4; ++j) {
      const int n = onb + j * 16;
      const float bj = bias[n];
#pragma unroll
      for (int i = 0; i < 4; ++i) {
        const int mrow = omb + i * 16;
        const int bb = mrow >> 11, t = mrow & (Tsz - 1);
        union { bf16 h[4]; uint2 u; } pk;
#pragma unroll
        for (int r = 0; r < 4; ++r) pk.h[r] = (bf16)(acc[i][j][r] + bj);
        *(uint2*)((bf16*)C + ((size_t)(bb * 1024 + n)) * Tsz + t) = pk.u;
      }
    }
  } else {
#pragma unroll
    for (int j = 0; j < 4; ++j) {
      const float bj = bias[onb + j * 16];
#pragma unroll
      for (int i = 0; i < 4; ++i) {
#pragma unroll
        for (int r = 0; r < 4; ++r) {
          const float v = acc[i][j][r] + bj;
          const size_t off = (size_t)(omb + i * 16 + r) * N + onb + j * 16;
          if constexpr (sizeof(OutT) == 2)
            C[off] = (OutT)v;
          else
            C[off] = v;
        }
      }
    }
  }
}

// ---------------------------------------------------------------------------
// Flash attention, bf16 MFMA. grid (T/128, B*H) heavy-first, 512 thr = 8
// waves; wave w owns q rows i0+w*16..+15. 64-key tiles staged with
// global_load_lds into XOR-swizzled unpadded LDS (chunk ^= row&7 on the
// GLOBAL address; frag reads invert). Softmax in exp2 domain.
// ---------------------------------------------------------------------------
__global__ __launch_bounds__(512) void attn_mfma(const bf16* __restrict__ Q,
                                                 const bf16* __restrict__ K,
                                                 const bf16* __restrict__ Vt,
                                                 bf16* __restrict__ Y) {
  __shared__ bf16 Ks[64 * 64];
  __shared__ bf16 Vs[64 * 64];
  __shared__ bf16 Ps[8][1024];

  const int bh = blockIdx.y;
  const int b = bh >> 4, h = bh & 15;
  const int i0 = (int)(gridDim.x - 1 - blockIdx.x) * 128;  // heavy-first
  const int tid = threadIdx.x;
  const int wave = tid >> 6, lane = tid & 63;
  const int l15 = lane & 15, quad = lane >> 4;

  // staging geometry: 512 lanes x 16B = one 64x64 bf16 tile
  const int srow = tid >> 3;
  const int gchunk = (tid & 7) ^ (srow & 7);
  const bf16* kbase = K + ((size_t)(b * Tsz + srow) * Csz + h * HDsz + gchunk * 8);
  const bf16* vbase = Vt + ((size_t)(bh * HDsz + srow) * Tsz + gchunk * 8);

  // Q A-frags in registers for the whole kernel
  bf16x8 qf0, qf1;
  {
    const bf16* qp =
        Q + ((size_t)(b * Tsz + i0 + wave * 16 + l15)) * Csz + h * HDsz + quad * 8;
    qf0 = *(const bf16x8*)qp;
    qf1 = *(const bf16x8*)(qp + 32);
  }

  const float sc = 0.180336880111124f;  // 0.125 * log2(e)  (exp2 domain)

  float4v Of[4];
  float m[4], l[4];
#pragma unroll
  for (int nc = 0; nc < 4; ++nc) Of[nc] = (float4v){0.f, 0.f, 0.f, 0.f};
#pragma unroll
  for (int r = 0; r < 4; ++r) {
    m[r] = -1e30f;
    l[r] = 0.f;
  }

  const int qg = i0 + wave * 16 + quad * 4;  // lane's first global q row
  const int wqe = i0 + wave * 16 + 15;       // wave's last global q row

  for (int j0 = 0; j0 <= i0 + 64; j0 += 64) {
    __syncthreads();
    GLOAD_LDS16(kbase + (size_t)j0 * Csz, &Ks[tid * 8]);
    GLOAD_LDS16(vbase + j0, &Vs[tid * 8]);
    __syncthreads();  // vmcnt(0) drained here

    if (j0 <= wqe) {  // wave-uniform: skip fully-masked tail tile
      // S = Q K^T
      float4v S[4];
#pragma unroll
      for (int nc = 0; nc < 4; ++nc) {
        const int row = nc * 16 + l15;
        const bf16x8 k0 =
            *(const bf16x8*)&Ks[row * 64 + ((quad ^ (row & 7)) * 8)];
        const bf16x8 k1 =
            *(const bf16x8*)&Ks[row * 64 + (((quad + 4) ^ (row & 7)) * 8)];
        float4v a = (float4v){0.f, 0.f, 0.f, 0.f};
        a = MFMA16(qf0, k0, a);
        a = MFMA16(qf1, k1, a);
        S[nc] = a;
      }

      if (j0 + 63 > i0 + wave * 16) {  // masking needed (wave-uniform)
#pragma unroll
        for (int nc = 0; nc < 4; ++nc)
#pragma unroll
          for (int r = 0; r < 4; ++r) {
            float s = S[nc][r] * sc;
            if (j0 + nc * 16 + l15 > qg + r) s = -1e30f;
            S[nc][r] = s;
          }
      } else {
#pragma unroll
        for (int nc = 0; nc < 4; ++nc)
#pragma unroll
          for (int r = 0; r < 4; ++r) S[nc][r] *= sc;
      }

      // online softmax (exp2 domain), per C-row r
#pragma unroll
      for (int r = 0; r < 4; ++r) {
        float mt = fmaxf(fmaxf(S[0][r], S[1][r]), fmaxf(S[2][r], S[3][r]));
#pragma unroll
        for (int off = 1; off <= 8; off <<= 1)
          mt = fmaxf(mt, __shfl_xor(mt, off));
        const float mn = fmaxf(m[r], mt);
        const float al = __builtin_amdgcn_exp2f(m[r] - mn);
        float ps = 0.f;
#pragma unroll
        for (int nc = 0; nc < 4; ++nc) {
          const float p = __builtin_amdgcn_exp2f(S[nc][r] - mn);
          S[nc][r] = p;
          ps += p;
        }
#pragma unroll
        for (int off = 1; off <= 8; off <<= 1) ps += __shfl_xor(ps, off);
        l[r] = l[r] * al + ps;
        m[r] = mn;
#pragma unroll
        for (int nc = 0; nc < 4; ++nc) Of[nc][r] *= al;
      }

      // P -> per-wave LDS in A-frag-linear order
#pragma unroll
      for (int nc = 0; nc < 4; ++nc) {
        const int keyl = nc * 16 + l15;
        const int kc = keyl >> 5;
        const int jj = keyl & 7;
        const int Lhi = ((keyl >> 3) & 3) * 16;
#pragma unroll
        for (int r = 0; r < 4; ++r) {
          const int L = Lhi + quad * 4 + r;
          Ps[wave][kc * 512 + L * 8 + jj] = (bf16)S[nc][r];
        }
      }

      const bf16x8 pf0 = *(const bf16x8*)&Ps[wave][0 * 512 + lane * 8];
      const bf16x8 pf1 = *(const bf16x8*)&Ps[wave][1 * 512 + lane * 8];
#pragma unroll
      for (int nc = 0; nc < 4; ++nc) {
        const int row = nc * 16 + l15;
        const bf16x8 v0 =
            *(const bf16x8*)&Vs[row * 64 + ((quad ^ (row & 7)) * 8)];
        const bf16x8 v1 =
            *(const bf16x8*)&Vs[row * 64 + (((quad + 4) ^ (row & 7)) * 8)];
        Of[nc] = MFMA16(pf0, v0, Of[nc]);
        Of[nc] = MFMA16(pf1, v1, Of[nc]);
      }
    }
  }

#pragma unroll
  for (int nc = 0; nc < 4; ++nc) {
#pragma unroll
    for (int r = 0; r < 4; ++r) {
      const size_t row = (size_t)b * Tsz + i0 + wave * 16 + quad * 4 + r;
      Y[row * Csz + h * HDsz + nc * 16 + l15] = (bf16)(Of[nc][r] / l[r]);
    }
  }
}

extern "C" void kernel_launch(void* const* d_in, const int* in_sizes, int n_in,
                              void* d_out, int out_size, void* d_ws,
                              size_t ws_size, hipStream_t stream) {
  const float* query = (const float*)d_in[0];
  const float* key = (const float*)d_in[1];
  const float* value = (const float*)d_in[2];
  // d_in[3] = att_mask (tril causal) -- hard-coded in attn kernel
  const float* Wq = (const float*)d_in[4];
  const float* bq = (const float*)d_in[5];
  const float* Wk = (const float*)d_in[6];
  const float* bk = (const float*)d_in[7];
  const float* Wv = (const float*)d_in[8];
  const float* bv = (const float*)d_in[9];
  const float* Wp = (const float*)d_in[10];
  const float* bp = (const float*)d_in[11];
  float* out = (float*)d_out;

  // ws map (40MB): WT[4] @0-8, vc @8-16 (reused as Yb after V-proj consumed),
  // Qp @16-24, Kp @24-32, Vt @32-40.  d_out doubles as qc/kc cast scratch
  // (dead before the final GEMM overwrites d_out).
  char* ws = (char*)d_ws;
  bf16* WT = (bf16*)(ws);
  bf16* vc = (bf16*)(ws + (8u << 20));
  bf16* Qp = (bf16*)(ws + (16u << 20));
  bf16* Kp = (bf16*)(ws + (24u << 20));
  bf16* Vt = (bf16*)(ws + (32u << 20));
  bf16* Yb = vc;
  bf16* qc = (bf16*)d_out;
  bf16* kc = (bf16*)((char*)d_out + (8u << 20));

  const int M = Bsz * Tsz;  // 4096

  cast3_bf16<<<dim3((M * Csz) / (256 * 8), 1, 3), dim3(256), 0, stream>>>(
      query, key, value, qc, kc, vc);
  wtrans_bf16<<<dim3(16, 16, 4), dim3(256), 0, stream>>>(Wq, Wk, Wv, Wp, WT);
  // batched QKV projection; z==2 writes Vt layout directly (fused transpose)
  gemm_mfma<bf16, true><<<dim3(Csz / 128, M / 128, 3), dim3(256), 0, stream>>>(
      qc, kc, vc, WT, bq, bk, bv, Qp, Kp, Vt, M, Csz, Csz);
  // flash attention (writes bf16 into Yb = old vc slot)
  attn_mfma<<<dim3(Tsz / 128, Bsz * Hsz), dim3(512), 0, stream>>>(Qp, Kp, Vt,
                                                                  Yb);
  // output projection (f32 into d_out)
  gemm_mfma<float, false><<<dim3(Csz / 128, M / 128, 1), dim3(256), 0, stream>>>(
      Yb, Yb, Yb, WT + 3u * (Csz * Csz), bp, bp, bp, out, out, out, M, Csz,
      Csz);
}

// Round 5
// 306.934 us; speedup vs baseline: 10.6887x; 1.0295x over previous
//
#include <hip/hip_runtime.h>

// B=2, T=2048, C=1024, H=16, HD=64, ALPHA=32
// softmax((att - globalmax)*ALPHA) == softmax(att*ALPHA): the global-max shift
// cancels (softmax shift-invariant; -inf mask applied after the shift).
// Net: causal SDPA with scale 1/sqrt(HD)=0.125, all matmuls in bf16 MFMA.
// Q is pre-scaled by 0.125*log2(e) in the QKV-projection epilogue so the
// attention softmax runs in the exp2 domain with no per-score multiply.

#define Bsz 2
#define Tsz 2048
#define Csz 1024
#define Hsz 16
#define HDsz 64

typedef __bf16 bf16;
typedef __bf16 bf16x8 __attribute__((ext_vector_type(8)));
typedef float float4v __attribute__((ext_vector_type(4)));

#define MFMA16(a, b, c) __builtin_amdgcn_mfma_f32_16x16x32_bf16(a, b, c, 0, 0, 0)

// async global->LDS, 16B per lane; LDS dest must be lane-linear within a wave
#define GLOAD_LDS16(gptr, lptr)                                      \
  __builtin_amdgcn_global_load_lds(                                  \
      (const __attribute__((address_space(1))) void*)(gptr),         \
      (__attribute__((address_space(3))) void*)(lptr), 16, 0, 0)

// ---------------------------------------------------------------------------
// cast f32 -> bf16, 3 tensors batched via grid.z, 8 elems/thread
// ---------------------------------------------------------------------------
__global__ __launch_bounds__(256) void cast3_bf16(
    const float* __restrict__ q, const float* __restrict__ k,
    const float* __restrict__ v, bf16* __restrict__ oq,
    bf16* __restrict__ ok, bf16* __restrict__ ov) {
  const int z = blockIdx.z;
  const float* src = z == 0 ? q : (z == 1 ? k : v);
  bf16* dst = z == 0 ? oq : (z == 1 ? ok : ov);
  const size_t i = ((size_t)blockIdx.x * 256 + threadIdx.x) * 8;
  const float4 a = *(const float4*)(src + i);
  const float4 b = *(const float4*)(src + i + 4);
  bf16x8 o;
  o[0] = (bf16)a.x; o[1] = (bf16)a.y; o[2] = (bf16)a.z; o[3] = (bf16)a.w;
  o[4] = (bf16)b.x; o[5] = (bf16)b.y; o[6] = (bf16)b.z; o[7] = (bf16)b.w;
  *(bf16x8*)(dst + i) = o;
}

// ---------------------------------------------------------------------------
// weight transpose+cast: W[K,N] f32 -> WT[N,K] bf16; grid.z selects Wq/Wk/Wv/Wp
// ---------------------------------------------------------------------------
__global__ __launch_bounds__(256) void wtrans_bf16(
    const float* __restrict__ Wq, const float* __restrict__ Wk,
    const float* __restrict__ Wv, const float* __restrict__ Wp,
    bf16* __restrict__ WT) {
  const int z = blockIdx.z;
  const float* W = z == 0 ? Wq : (z == 1 ? Wk : (z == 2 ? Wv : Wp));
  bf16* out = WT + (size_t)z * (Csz * Csz);
  __shared__ float Ts[64][68];
  const int k0 = blockIdx.y * 64, n0 = blockIdx.x * 64;
  const int tid = threadIdx.x;
#pragma unroll
  for (int it = 0; it < 4; ++it) {
    const int idx = it * 256 + tid;
    const int r = idx >> 4, c4 = (idx & 15) * 4;
    *(float4*)&Ts[r][c4] = *(const float4*)(W + (size_t)(k0 + r) * Csz + n0 + c4);
  }
  __syncthreads();
#pragma unroll
  for (int it = 0; it < 2; ++it) {
    const int idx = it * 256 + tid;
    const int n = idx & 63, k8 = (idx >> 6) * 8;
    bf16x8 o;
#pragma unroll
    for (int j = 0; j < 8; ++j) o[j] = (bf16)Ts[k8 + j][n];
    *(bf16x8*)(out + (size_t)(n0 + n) * Csz + k0 + k8) = o;
  }
}

// ---------------------------------------------------------------------------
// bf16 MFMA GEMM (m97 structure): C[M,N] = (A[M,K] @ Bt[N,K]^T + bias) * osc
// 128x128 tile, BK=32, 256 thr = 4 waves (2x2), wave does 4x4 16x16 tiles.
// grid.z batches up to 3. VTR(=QKV instance): z==0 scales output by
// 0.125*log2(e) (softmax pre-scale); z==2 writes Vt[B*H, HD, T] layout
// (fused V-transpose).
// ---------------------------------------------------------------------------
template <typename OutT, bool VTR>
__global__ __launch_bounds__(256) void gemm_mfma(
    const bf16* __restrict__ A0, const bf16* __restrict__ A1,
    const bf16* __restrict__ A2, const bf16* __restrict__ Wt,
    const float* __restrict__ b0, const float* __restrict__ b1,
    const float* __restrict__ b2, OutT* __restrict__ C0,
    OutT* __restrict__ C1, OutT* __restrict__ C2, int M, int N, int K) {
  const int z = blockIdx.z;
  const bf16* A = z == 0 ? A0 : (z == 1 ? A1 : A2);
  const float* bias = z == 0 ? b0 : (z == 1 ? b1 : b2);
  OutT* C = z == 0 ? C0 : (z == 1 ? C1 : C2);
  const bf16* Bt = Wt + (size_t)z * N * K;
  const float osc = (VTR && z == 0) ? 0.180336880111124f : 1.0f;

  __shared__ bf16 As[128 * 32];
  __shared__ bf16 Bs[128 * 32];
  const int tid = threadIdx.x;
  const int wave = tid >> 6, lane = tid & 63;
  const int l15 = lane & 15, quad = lane >> 4;
  const int m0 = blockIdx.y * 128, n0 = blockIdx.x * 128;
  const int wm = (wave >> 1) * 64, wn = (wave & 1) * 64;
  const int srow = tid >> 2, schunk = tid & 3;

  float4v acc[4][4];
#pragma unroll
  for (int i = 0; i < 4; ++i)
#pragma unroll
    for (int j = 0; j < 4; ++j) acc[i][j] = (float4v){0.f, 0.f, 0.f, 0.f};

  for (int k0 = 0; k0 < K; k0 += 32) {
    __syncthreads();
#pragma unroll
    for (int p = 0; p < 2; ++p) {
      const int row = p * 64 + srow;
      GLOAD_LDS16(A + (size_t)(m0 + row) * K + k0 + schunk * 8,
                  &As[(p * 256 + tid) * 8]);
      GLOAD_LDS16(Bt + (size_t)(n0 + row) * K + k0 + schunk * 8,
                  &Bs[(p * 256 + tid) * 8]);
    }
    __syncthreads();

    bf16x8 af[4], bfr[4];
#pragma unroll
    for (int i = 0; i < 4; ++i)
      af[i] = *(const bf16x8*)&As[(wm + i * 16 + l15) * 32 + quad * 8];
#pragma unroll
    for (int j = 0; j < 4; ++j)
      bfr[j] = *(const bf16x8*)&Bs[(wn + j * 16 + l15) * 32 + quad * 8];
#pragma unroll
    for (int i = 0; i < 4; ++i)
#pragma unroll
      for (int j = 0; j < 4; ++j)
        acc[i][j] = MFMA16(af[i], bfr[j], acc[i][j]);
  }

  // C-layout per 16x16 tile: D[m=quad*4+r][n=l15] (m89-verified)
  const int omb = m0 + wm + quad * 4;
  const int onb = n0 + wn + l15;
  if (VTR && z == 2) {
    // fused V transpose: Vt[(b*1024 + n)][t] = v
#pragma unroll
    for (int j = 0; j < 4; ++j) {
      const int n = onb + j * 16;
      const float bj = bias[n];
#pragma unroll
      for (int i = 0; i < 4; ++i) {
        const int mrow = omb + i * 16;
        const int bb = mrow >> 11, t = mrow & (Tsz - 1);
        union { bf16 h[4]; uint2 u; } pk;
#pragma unroll
        for (int r = 0; r < 4; ++r) pk.h[r] = (bf16)(acc[i][j][r] + bj);
        *(uint2*)((bf16*)C + ((size_t)(bb * 1024 + n)) * Tsz + t) = pk.u;
      }
    }
  } else {
#pragma unroll
    for (int j = 0; j < 4; ++j) {
      const float bj = bias[onb + j * 16];
#pragma unroll
      for (int i = 0; i < 4; ++i) {
#pragma unroll
        for (int r = 0; r < 4; ++r) {
          const float v = (acc[i][j][r] + bj) * osc;
          const size_t off = (size_t)(omb + i * 16 + r) * N + onb + j * 16;
          if constexpr (sizeof(OutT) == 2)
            C[off] = (OutT)v;
          else
            C[off] = v;
        }
      }
    }
  }
}

// ---------------------------------------------------------------------------
// Flash attention, bf16 MFMA, DOUBLE-BUFFERED K/V staging (one barrier/iter:
// issue tile t+1's global_load_lds right after the barrier, compute tile t;
// the compiler's vmcnt(0)-before-s_barrier then drains loads that had a full
// compute phase in flight). grid (T/128, B*H) heavy-first, 512 thr = 8 waves.
// Q arrives pre-scaled by 0.125*log2(e); softmax in exp2 domain.
// ---------------------------------------------------------------------------
__global__ __launch_bounds__(512) void attn_mfma(const bf16* __restrict__ Q,
                                                 const bf16* __restrict__ K,
                                                 const bf16* __restrict__ Vt,
                                                 bf16* __restrict__ Y) {
  __shared__ bf16 Ks[2][64 * 64];
  __shared__ bf16 Vs[2][64 * 64];
  __shared__ bf16 Ps[8][1024];

  const int bh = blockIdx.y;
  const int b = bh >> 4, h = bh & 15;
  const int i0 = (int)(gridDim.x - 1 - blockIdx.x) * 128;  // heavy-first
  const int tid = threadIdx.x;
  const int wave = tid >> 6, lane = tid & 63;
  const int l15 = lane & 15, quad = lane >> 4;

  // staging geometry: 512 lanes x 16B = one 64x64 bf16 tile
  const int srow = tid >> 3;
  const int gchunk = (tid & 7) ^ (srow & 7);  // XOR swizzle on global addr
  const bf16* kbase = K + ((size_t)(b * Tsz + srow) * Csz + h * HDsz + gchunk * 8);
  const bf16* vbase = Vt + ((size_t)(bh * HDsz + srow) * Tsz + gchunk * 8);

  // Q A-frags in registers for the whole kernel (pre-scaled)
  bf16x8 qf0, qf1;
  {
    const bf16* qp =
        Q + ((size_t)(b * Tsz + i0 + wave * 16 + l15)) * Csz + h * HDsz + quad * 8;
    qf0 = *(const bf16x8*)qp;
    qf1 = *(const bf16x8*)(qp + 32);
  }

  float4v Of[4];
  float m[4], l[4];
#pragma unroll
  for (int nc = 0; nc < 4; ++nc) Of[nc] = (float4v){0.f, 0.f, 0.f, 0.f};
#pragma unroll
  for (int r = 0; r < 4; ++r) {
    m[r] = -1e30f;
    l[r] = 0.f;
  }

  const int qg = i0 + wave * 16 + quad * 4;  // lane's first global q row
  const int wqe = i0 + wave * 16 + 15;       // wave's last global q row
  const int jlast = i0 + 64;

  // preload tile 0 into buffer 0
  GLOAD_LDS16(kbase, &Ks[0][tid * 8]);
  GLOAD_LDS16(vbase, &Vs[0][tid * 8]);

  for (int j0 = 0; j0 <= jlast; j0 += 64) {
    const int buf = (j0 >> 6) & 1;
    __syncthreads();  // tile j0 resident; prior reads of buf^1 complete
    if (j0 + 64 <= jlast) {  // prefetch next tile into the other buffer
      GLOAD_LDS16(kbase + (size_t)(j0 + 64) * Csz, &Ks[buf ^ 1][tid * 8]);
      GLOAD_LDS16(vbase + (j0 + 64), &Vs[buf ^ 1][tid * 8]);
    }

    if (j0 <= wqe) {  // wave-uniform: skip fully-masked tail tile
      // S = Q K^T
      float4v S[4];
#pragma unroll
      for (int nc = 0; nc < 4; ++nc) {
        const int row = nc * 16 + l15;
        const bf16x8 k0 =
            *(const bf16x8*)&Ks[buf][row * 64 + ((quad ^ (row & 7)) * 8)];
        const bf16x8 k1 =
            *(const bf16x8*)&Ks[buf][row * 64 + (((quad + 4) ^ (row & 7)) * 8)];
        float4v a = (float4v){0.f, 0.f, 0.f, 0.f};
        a = MFMA16(qf0, k0, a);
        a = MFMA16(qf1, k1, a);
        S[nc] = a;
      }

      if (j0 + 63 > i0 + wave * 16) {  // masking needed (wave-uniform)
#pragma unroll
        for (int nc = 0; nc < 4; ++nc)
#pragma unroll
          for (int r = 0; r < 4; ++r)
            if (j0 + nc * 16 + l15 > qg + r) S[nc][r] = -1e30f;
      }

      // online softmax (exp2 domain; Q pre-scaled), per C-row r
#pragma unroll
      for (int r = 0; r < 4; ++r) {
        float mt = fmaxf(fmaxf(S[0][r], S[1][r]), fmaxf(S[2][r], S[3][r]));
#pragma unroll
        for (int off = 1; off <= 8; off <<= 1)
          mt = fmaxf(mt, __shfl_xor(mt, off));
        const float mn = fmaxf(m[r], mt);
        const float al = __builtin_amdgcn_exp2f(m[r] - mn);
        float ps = 0.f;
#pragma unroll
        for (int nc = 0; nc < 4; ++nc) {
          const float p = __builtin_amdgcn_exp2f(S[nc][r] - mn);
          S[nc][r] = p;
          ps += p;
        }
#pragma unroll
        for (int off = 1; off <= 8; off <<= 1) ps += __shfl_xor(ps, off);
        l[r] = l[r] * al + ps;
        m[r] = mn;
#pragma unroll
        for (int nc = 0; nc < 4; ++nc) Of[nc][r] *= al;
      }

      // P -> per-wave LDS in A-frag-linear order
#pragma unroll
      for (int nc = 0; nc < 4; ++nc) {
        const int keyl = nc * 16 + l15;
        const int kc = keyl >> 5;
        const int jj = keyl & 7;
        const int Lhi = ((keyl >> 3) & 3) * 16;
#pragma unroll
        for (int r = 0; r < 4; ++r) {
          const int L = Lhi + quad * 4 + r;
          Ps[wave][kc * 512 + L * 8 + jj] = (bf16)S[nc][r];
        }
      }

      const bf16x8 pf0 = *(const bf16x8*)&Ps[wave][0 * 512 + lane * 8];
      const bf16x8 pf1 = *(const bf16x8*)&Ps[wave][1 * 512 + lane * 8];
#pragma unroll
      for (int nc = 0; nc < 4; ++nc) {
        const int row = nc * 16 + l15;
        const bf16x8 v0 =
            *(const bf16x8*)&Vs[buf][row * 64 + ((quad ^ (row & 7)) * 8)];
        const bf16x8 v1 =
            *(const bf16x8*)&Vs[buf][row * 64 + (((quad + 4) ^ (row & 7)) * 8)];
        Of[nc] = MFMA16(pf0, v0, Of[nc]);
        Of[nc] = MFMA16(pf1, v1, Of[nc]);
      }
    }
  }

#pragma unroll
  for (int r = 0; r < 4; ++r) l[r] = __builtin_amdgcn_rcpf(l[r]);
#pragma unroll
  for (int nc = 0; nc < 4; ++nc) {
#pragma unroll
    for (int r = 0; r < 4; ++r) {
      const size_t row = (size_t)b * Tsz + i0 + wave * 16 + quad * 4 + r;
      Y[row * Csz + h * HDsz + nc * 16 + l15] = (bf16)(Of[nc][r] * l[r]);
    }
  }
}

extern "C" void kernel_launch(void* const* d_in, const int* in_sizes, int n_in,
                              void* d_out, int out_size, void* d_ws,
                              size_t ws_size, hipStream_t stream) {
  const float* query = (const float*)d_in[0];
  const float* key = (const float*)d_in[1];
  const float* value = (const float*)d_in[2];
  // d_in[3] = att_mask (tril causal) -- hard-coded in attn kernel
  const float* Wq = (const float*)d_in[4];
  const float* bq = (const float*)d_in[5];
  const float* Wk = (const float*)d_in[6];
  const float* bk = (const float*)d_in[7];
  const float* Wv = (const float*)d_in[8];
  const float* bv = (const float*)d_in[9];
  const float* Wp = (const float*)d_in[10];
  const float* bp = (const float*)d_in[11];
  float* out = (float*)d_out;

  // ws map (40MB): WT[4] @0-8, vc @8-16 (reused as Yb after V-proj consumed),
  // Qp @16-24, Kp @24-32, Vt @32-40.  d_out doubles as qc/kc cast scratch
  // (dead before the final GEMM overwrites d_out).
  char* ws = (char*)d_ws;
  bf16* WT = (bf16*)(ws);
  bf16* vc = (bf16*)(ws + (8u << 20));
  bf16* Qp = (bf16*)(ws + (16u << 20));
  bf16* Kp = (bf16*)(ws + (24u << 20));
  bf16* Vt = (bf16*)(ws + (32u << 20));
  bf16* Yb = vc;
  bf16* qc = (bf16*)d_out;
  bf16* kc = (bf16*)((char*)d_out + (8u << 20));

  const int M = Bsz * Tsz;  // 4096

  cast3_bf16<<<dim3((M * Csz) / (256 * 8), 1, 3), dim3(256), 0, stream>>>(
      query, key, value, qc, kc, vc);
  wtrans_bf16<<<dim3(16, 16, 4), dim3(256), 0, stream>>>(Wq, Wk, Wv, Wp, WT);
  // batched QKV projection; z==0 pre-scales Q; z==2 writes Vt layout
  gemm_mfma<bf16, true><<<dim3(Csz / 128, M / 128, 3), dim3(256), 0, stream>>>(
      qc, kc, vc, WT, bq, bk, bv, Qp, Kp, Vt, M, Csz, Csz);
  // flash attention (writes bf16 into Yb = old vc slot)
  attn_mfma<<<dim3(Tsz / 128, Bsz * Hsz), dim3(512), 0, stream>>>(Qp, Kp, Vt,
                                                                  Yb);
  // output projection (f32 into d_out)
  gemm_mfma<float, false><<<dim3(Csz / 128, M / 128, 1), dim3(256), 0, stream>>>(
      Yb, Yb, Yb, WT + 3u * (Csz * Csz), bp, bp, bp, out, out, out, M, Csz,
      Csz);
}